// Round 6
// baseline (178.940 us; speedup 1.0000x reference)
//
#include <hip/hip_runtime.h>
#include <math.h>

// ---------------------------------------------------------------------------
// Host-side: build stiffness matrix C = inv(Ci) in double precision (faithful
// to np.linalg.inv of the block-diagonal compliance matrix).
// ---------------------------------------------------------------------------
struct CParams {
    float b[3][3];  // inverse of the upper-left 3x3 compliance block
    float s;        // shear stiffness diagonal = Ep / (2*(1+vp)) = 0.075
};

static CParams make_C() {
    const double vp = 0.4, Ep = 0.21;
    double A[3][3] = {
        {1.0 / Ep, -vp / Ep, -vp / Ep},
        {-vp / Ep, 1.0 / Ep, -vp / Ep},
        {-vp,      -vp,      1.0 / Ep},   // note: -vp, NOT -vp/Ep (faithful)
    };
    double inv[3][3] = {{1, 0, 0}, {0, 1, 0}, {0, 0, 1}};
    for (int col = 0; col < 3; ++col) {
        int piv = col;
        for (int r = col + 1; r < 3; ++r)
            if (fabs(A[r][col]) > fabs(A[piv][col])) piv = r;
        if (piv != col) {
            for (int c = 0; c < 3; ++c) {
                double t = A[col][c]; A[col][c] = A[piv][c]; A[piv][c] = t;
                t = inv[col][c]; inv[col][c] = inv[piv][c]; inv[piv][c] = t;
            }
        }
        double d = A[col][col];
        for (int c = 0; c < 3; ++c) { A[col][c] /= d; inv[col][c] /= d; }
        for (int r = 0; r < 3; ++r) {
            if (r == col) continue;
            double f = A[r][col];
            for (int c = 0; c < 3; ++c) {
                A[r][c] -= f * A[col][c];
                inv[r][c] -= f * inv[col][c];
            }
        }
    }
    CParams p;
    for (int i = 0; i < 3; ++i)
        for (int j = 0; j < 3; ++j)
            p.b[i][j] = (float)inv[i][j];
    p.s = (float)(Ep / (2.0 * (1.0 + vp)));
    return p;
}

static const CParams g_C = make_C();

#define MAXB 2048   // partial-sum slots in workspace (and max grid)
#define TPB  256    // threads per block (4 waves)
#define PPT  8      // points per thread -> 20 float4 loads per burst

// ---------------------------------------------------------------------------
// Max-MLP probe. Each thread owns 8 consecutive points and issues ALL 20
// float4 loads (6 u + 6 v + 6 w + 2 sdf = 320 B) as one burst before any
// consumption — ~80 payload VGPRs in flight per thread, no LDS round-trip,
// no barriers, no waitcnt until the burst is fully issued. 524,288 threads
// cover N=4.19M exactly (2048 blocks, 2 block-rounds/CU at 16 waves/CU).
// __launch_bounds__(256,4): 4 waves/SIMD floor -> VGPR cap 128, no spill.
// R2/R5 post-mortem: coalescing and barriers were neutral; both compiled to
// 32-56 VGPRs (<=10 loads in flight) -> latency-bound. This kernel tests
// whether per-wave MLP is the wall.
// ---------------------------------------------------------------------------
__global__ __launch_bounds__(TPB, 4) void biomech_reduce(
    const float* __restrict__ gu, const float* __restrict__ gv,
    const float* __restrict__ gw, const float* __restrict__ gs,
    float* __restrict__ ws, int n, CParams C)
{
    const int npack = n / PPT;

    const float4* u4 = (const float4*)gu;
    const float4* v4 = (const float4*)gv;
    const float4* w4 = (const float4*)gw;
    const float4* s4 = (const float4*)gs;

    float sumq2 = 0.0f, cnt = 0.0f;

    for (int i = blockIdx.x * TPB + threadIdx.x; i < npack;
         i += gridDim.x * TPB) {
        const int b6 = 6 * i;   // float4 base into u/v/w
        const int b2 = 2 * i;   // float4 base into sdf

        float4 U[6], V[6], W[6], S[2];
#pragma unroll
        for (int j = 0; j < 6; ++j) U[j] = u4[b6 + j];
#pragma unroll
        for (int j = 0; j < 6; ++j) V[j] = v4[b6 + j];
#pragma unroll
        for (int j = 0; j < 6; ++j) W[j] = w4[b6 + j];
        S[0] = s4[b2];
        S[1] = s4[b2 + 1];

        // spill vector regs into scalar arrays with constant indices (SROA
        // keeps these in VGPRs; no pointer casts that would force scratch)
        float uu[24], vv[24], ww[24], ss[8];
#pragma unroll
        for (int j = 0; j < 6; ++j) {
            uu[4 * j] = U[j].x; uu[4 * j + 1] = U[j].y;
            uu[4 * j + 2] = U[j].z; uu[4 * j + 3] = U[j].w;
            vv[4 * j] = V[j].x; vv[4 * j + 1] = V[j].y;
            vv[4 * j + 2] = V[j].z; vv[4 * j + 3] = V[j].w;
            ww[4 * j] = W[j].x; ww[4 * j + 1] = W[j].y;
            ww[4 * j + 2] = W[j].z; ww[4 * j + 3] = W[j].w;
        }
        ss[0] = S[0].x; ss[1] = S[0].y; ss[2] = S[0].z; ss[3] = S[0].w;
        ss[4] = S[1].x; ss[5] = S[1].y; ss[6] = S[1].z; ss[7] = S[1].w;

#pragma unroll
        for (int k = 0; k < PPT; ++k) {
            float e0 = uu[3 * k + 0];
            float e1 = vv[3 * k + 1];
            float e2 = ww[3 * k + 2];
            float e3 = 0.5f * (uu[3 * k + 1] + vv[3 * k + 0]);
            float e4 = 0.5f * (uu[3 * k + 2] + ww[3 * k + 0]);
            float e5 = 0.5f * (ww[3 * k + 1] + vv[3 * k + 2]);

            float q = e0 * (C.b[0][0] * e0 + C.b[0][1] * e1 + C.b[0][2] * e2)
                    + e1 * (C.b[1][0] * e0 + C.b[1][1] * e1 + C.b[1][2] * e2)
                    + e2 * (C.b[2][0] * e0 + C.b[2][1] * e1 + C.b[2][2] * e2)
                    + C.s * (e3 * e3 + e4 * e4 + e5 * e5);

            bool m = ss[k] < 1e-8f;
            float qm = m ? q : 0.0f;
            sumq2 += qm * qm;
            cnt   += m ? 1.0f : 0.0f;
        }
    }

    // Tail (n not divisible by PPT) — global thread 0 only.
    if (blockIdx.x == 0 && threadIdx.x == 0) {
        for (int i = (n / PPT) * PPT; i < n; ++i) {
            float e0 = gu[3 * i + 0];
            float e1 = gv[3 * i + 1];
            float e2 = gw[3 * i + 2];
            float e3 = 0.5f * (gu[3 * i + 1] + gv[3 * i + 0]);
            float e4 = 0.5f * (gu[3 * i + 2] + gw[3 * i + 0]);
            float e5 = 0.5f * (gw[3 * i + 1] + gv[3 * i + 2]);
            float q = e0 * (C.b[0][0] * e0 + C.b[0][1] * e1 + C.b[0][2] * e2)
                    + e1 * (C.b[1][0] * e0 + C.b[1][1] * e1 + C.b[1][2] * e2)
                    + e2 * (C.b[2][0] * e0 + C.b[2][1] * e1 + C.b[2][2] * e2)
                    + C.s * (e3 * e3 + e4 * e4 + e5 * e5);
            bool m = gs[i] < 1e-8f;
            float qm = m ? q : 0.0f;
            sumq2 += qm * qm;
            cnt   += m ? 1.0f : 0.0f;
        }
    }

    // Wave (64-lane) shuffle reduction
#pragma unroll
    for (int off = 32; off > 0; off >>= 1) {
        sumq2 += __shfl_down(sumq2, off);
        cnt   += __shfl_down(cnt, off);
    }

    __shared__ float ssum[4], scnt[4];
    const int wave = threadIdx.x >> 6;
    const int lane = threadIdx.x & 63;
    if (lane == 0) { ssum[wave] = sumq2; scnt[wave] = cnt; }
    __syncthreads();
    if (threadIdx.x == 0) {
        float s2 = 0.0f, c2 = 0.0f;
#pragma unroll
        for (int i = 0; i < 4; ++i) { s2 += ssum[i]; c2 += scnt[i]; }
        ws[blockIdx.x]        = s2;   // contention-free per-block store
        ws[MAXB + blockIdx.x] = c2;
    }
}

// ---------------------------------------------------------------------------
// Finalize: single block reduces nb partial pairs, writes sqrt(sum)/count.
// ---------------------------------------------------------------------------
__global__ __launch_bounds__(256) void biomech_finalize(
    const float* __restrict__ ws, float* __restrict__ out, int nb)
{
    float s = 0.0f, c = 0.0f;
    for (int i = threadIdx.x; i < nb; i += 256) {
        s += ws[i];
        c += ws[MAXB + i];
    }
#pragma unroll
    for (int off = 32; off > 0; off >>= 1) {
        s += __shfl_down(s, off);
        c += __shfl_down(c, off);
    }
    __shared__ float ssum[4], scnt[4];
    const int wave = threadIdx.x >> 6;
    const int lane = threadIdx.x & 63;
    if (lane == 0) { ssum[wave] = s; scnt[wave] = c; }
    __syncthreads();
    if (threadIdx.x == 0) {
        float s2 = ssum[0] + ssum[1] + ssum[2] + ssum[3];
        float c2 = scnt[0] + scnt[1] + scnt[2] + scnt[3];
        out[0] = sqrtf(s2) / c2;
    }
}

extern "C" void kernel_launch(void* const* d_in, const int* in_sizes, int n_in,
                              void* d_out, int out_size, void* d_ws, size_t ws_size,
                              hipStream_t stream) {
    const float* gu = (const float*)d_in[0];
    const float* gv = (const float*)d_in[1];
    const float* gw = (const float*)d_in[2];
    const float* gs = (const float*)d_in[3];
    float* ws = (float*)d_ws;
    float* out = (float*)d_out;

    const int n = in_sizes[3];      // number of points (gt_sdf length)
    const int npack = n / PPT;

    int grid = (npack + TPB - 1) / TPB;   // 2048 for N = 4.19M (exact cover)
    if (grid > MAXB) grid = MAXB;
    while (grid > 1 && (size_t)(MAXB + grid) * sizeof(float) > ws_size) grid >>= 1;
    if (grid < 1) grid = 1;

    biomech_reduce<<<grid, TPB, 0, stream>>>(gu, gv, gw, gs, ws, n, g_C);
    biomech_finalize<<<1, 256, 0, stream>>>(ws, out, grid);
}